// Round 6
// baseline (193.850 us; speedup 1.0000x reference)
//
#include <hip/hip_runtime.h>
#include <math.h>
#include <stdint.h>

#define NN 500000   // nodes
#define NB 4096     // segments
#define DD 256      // feature dim

typedef short  short8  __attribute__((ext_vector_type(8)));
typedef short  short4v __attribute__((ext_vector_type(4)));
typedef float  floatx4 __attribute__((ext_vector_type(4)));
typedef float  f2      __attribute__((ext_vector_type(2)));

__device__ __forceinline__ f2 sp(float v) { return (f2){v, v}; }

// fp32 -> bf16 round-to-nearest-even
__device__ __forceinline__ short f2bf(float f) {
    uint32_t u = __float_as_uint(f);
    u += 0x7fffu + ((u >> 16) & 1u);
    return (short)(u >> 16);
}

// Packed (2-wide) fast gelu: A&S 7.1.26 erf (|err| <= 1.5e-7), branchless.
__device__ __forceinline__ f2 gelu2(f2 x) {
    f2 z   = __builtin_elementwise_abs(x) * sp(0.70710678118654752440f);
    f2 den = __builtin_elementwise_fma(z, sp(0.3275911f), sp(1.0f));
    f2 t   = { __builtin_amdgcn_rcpf(den.x), __builtin_amdgcn_rcpf(den.y) };
    f2 p   = __builtin_elementwise_fma(sp(1.061405429f), t, sp(-1.453152027f));
    p = __builtin_elementwise_fma(p, t, sp(1.421413741f));
    p = __builtin_elementwise_fma(p, t, sp(-0.284496736f));
    p = __builtin_elementwise_fma(p, t, sp(0.254829592f));
    p = p * t;
    f2 ez  = { __expf(-z.x * z.x), __expf(-z.y * z.y) };
    f2 er  = __builtin_elementwise_copysign(sp(1.0f) - p * ez, x);
    return sp(0.5f) * x * (sp(1.0f) + er);
}

// ---------------------------------------------------------------------------
// seg_kernel v3: one block (4 waves) per segment; wave handles a contiguous
// chunk. Lane = 32*g + j: sub-wave g in {0,1} processes row pair-member g,
// lane owns cols 8j..8j+7. Head (64 cols) = 8 lanes -> 3-step shfl reduce,
// one shuffle instruction serves 2 rows. 2-pair software pipeline (4 rows in
// flight). Plain-exp segment softmax (logits small). Cross-g combine via
// shfl_xor(32); cross-wave via 20.5 KB LDS.
// ---------------------------------------------------------------------------
__global__ __launch_bounds__(256) void seg_kernel(
    const float* __restrict__ x,
    const int*   __restrict__ seg,
    const float* __restrict__ att_w,
    float* __restrict__ merged,    // (NB, 1024)
    float* __restrict__ center,    // (NB, 256)
    float* __restrict__ neighbor)  // (NB, 256)
{
    const int b   = blockIdx.x;
    const int tid = threadIdx.x;
    const int w   = tid >> 6;     // wave 0..3
    const int l   = tid & 63;     // lane
    const int g   = l >> 5;       // row within pair
    const int j   = l & 31;       // col group (8 cols)

    // wave-uniform binary search: [start, end) rows of segment b
    int lo = 0, hi = NN;
    while (lo < hi) { int mid = (lo + hi) >> 1; if (seg[mid] < b) lo = mid + 1; else hi = mid; }
    const int start = lo;
    hi = NN;
    while (lo < hi) { int mid = (lo + hi) >> 1; if (seg[mid] <= b) lo = mid + 1; else hi = mid; }
    const int end = lo;

    // contiguous chunk for this wave
    const int cnt = end - start;
    const int q = cnt >> 2, r4 = cnt & 3;
    const int my_start = start + w * q + (w < r4 ? w : r4);
    const int my_cnt   = q + (w < r4 ? 1 : 0);

    const float4 awa = *reinterpret_cast<const float4*>(&att_w[8 * j]);
    const float4 awb = *reinterpret_cast<const float4*>(&att_w[8 * j + 4]);
    const f2 aw0 = {awa.x, awa.y}, aw1 = {awa.z, awa.w};
    const f2 aw2 = {awb.x, awb.y}, aw3 = {awb.z, awb.w};

    f2 cA[4] = {sp(0.f), sp(0.f), sp(0.f), sp(0.f)};
    f2 nA[4] = {sp(-INFINITY), sp(-INFINITY), sp(-INFINITY), sp(-INFINITY)};
    f2 sA[4] = {sp(0.f), sp(0.f), sp(0.f), sp(0.f)};
    f2 mA[4] = {sp(-INFINITY), sp(-INFINITY), sp(-INFINITY), sp(-INFINITY)};
    f2 aA[4] = {sp(0.f), sp(0.f), sp(0.f), sp(0.f)};
    float lsum = 0.f;

    const float* __restrict__ xr = x + 8 * j;
    auto LD2 = [&](int row, float4& u0, float4& u1) {
        int rc = row < NN ? row : (NN - 1);    // clamp; over-reads discarded
        const float* p = &xr[(size_t)rc * DD];
        u0 = *reinterpret_cast<const float4*>(p);
        u1 = *reinterpret_cast<const float4*>(p + 4);
    };

    auto process = [&](const float4& u0, const float4& u1) {
        f2 p0 = {u0.x, u0.y}, p1 = {u0.z, u0.w};
        f2 p2 = {u1.x, u1.y}, p3 = {u1.z, u1.w};
        f2 g0 = gelu2(p0), g1 = gelu2(p1), g2 = gelu2(p2), g3 = gelu2(p3);
        cA[0] += g0; cA[1] += g1; cA[2] += g2; cA[3] += g3;
        nA[0] = __builtin_elementwise_max(nA[0], g0);
        nA[1] = __builtin_elementwise_max(nA[1], g1);
        nA[2] = __builtin_elementwise_max(nA[2], g2);
        nA[3] = __builtin_elementwise_max(nA[3], g3);
        sA[0] += p0; sA[1] += p1; sA[2] += p2; sA[3] += p3;
        mA[0] = __builtin_elementwise_max(mA[0], p0);
        mA[1] = __builtin_elementwise_max(mA[1], p1);
        mA[2] = __builtin_elementwise_max(mA[2], p2);
        mA[3] = __builtin_elementwise_max(mA[3], p3);
        f2 tp = p0 * aw0;
        tp = __builtin_elementwise_fma(p1, aw1, tp);
        tp = __builtin_elementwise_fma(p2, aw2, tp);
        tp = __builtin_elementwise_fma(p3, aw3, tp);
        float t = tp.x + tp.y;
        t += __shfl_xor(t, 1, 64);
        t += __shfl_xor(t, 2, 64);
        t += __shfl_xor(t, 4, 64);      // sum over the 8-lane head group
        float alpha = fmaxf(t, 0.2f * t);   // leaky_relu 0.2
        float e = __expf(alpha);            // no max-shift: |alpha| small
        lsum += e;
        f2 ev = sp(e);
        aA[0] = __builtin_elementwise_fma(ev, p0, aA[0]);
        aA[1] = __builtin_elementwise_fma(ev, p1, aA[1]);
        aA[2] = __builtin_elementwise_fma(ev, p2, aA[2]);
        aA[3] = __builtin_elementwise_fma(ev, p3, aA[3]);
    };

    // pair t covers rows base+2t (g=0) and base+2t+1 (g=1)
    const int base = my_start + g;
    const int full = my_cnt >> 1;        // pairs with both rows valid
    float4 A0, A1, B0, B1;
    LD2(base,     A0, A1);
    LD2(base + 2, B0, B1);
    for (int t = 0; t < full; ++t) {
        float4 C0, C1;
        LD2(base + 2 * t + 4, C0, C1);
        process(A0, A1);
        A0 = B0; A1 = B1; B0 = C0; B1 = C1;
    }
    if (my_cnt & 1) {
        if (g == 0) process(A0, A1);     // divergent partners share g; safe
    }

    // ---- combine g halves in-register (lane ^ 32 has the other row set) ----
    #pragma unroll
    for (int k = 0; k < 4; ++k) {
        cA[k].x += __shfl_xor(cA[k].x, 32, 64); cA[k].y += __shfl_xor(cA[k].y, 32, 64);
        sA[k].x += __shfl_xor(sA[k].x, 32, 64); sA[k].y += __shfl_xor(sA[k].y, 32, 64);
        aA[k].x += __shfl_xor(aA[k].x, 32, 64); aA[k].y += __shfl_xor(aA[k].y, 32, 64);
        nA[k].x = fmaxf(nA[k].x, __shfl_xor(nA[k].x, 32, 64));
        nA[k].y = fmaxf(nA[k].y, __shfl_xor(nA[k].y, 32, 64));
        mA[k].x = fmaxf(mA[k].x, __shfl_xor(mA[k].x, 32, 64));
        mA[k].y = fmaxf(mA[k].y, __shfl_xor(mA[k].y, 32, 64));
    }
    lsum += __shfl_xor(lsum, 32, 64);

    // ---- cross-wave combine via LDS ----
    __shared__ float lds[5][4][256];   // 20 KB
    __shared__ float ldsl[4][4];
    if (g == 0) {
        const int cb = 8 * j;
        *(float4*)&lds[0][w][cb]   = (float4){cA[0].x, cA[0].y, cA[1].x, cA[1].y};
        *(float4*)&lds[0][w][cb+4] = (float4){cA[2].x, cA[2].y, cA[3].x, cA[3].y};
        *(float4*)&lds[1][w][cb]   = (float4){nA[0].x, nA[0].y, nA[1].x, nA[1].y};
        *(float4*)&lds[1][w][cb+4] = (float4){nA[2].x, nA[2].y, nA[3].x, nA[3].y};
        *(float4*)&lds[2][w][cb]   = (float4){sA[0].x, sA[0].y, sA[1].x, sA[1].y};
        *(float4*)&lds[2][w][cb+4] = (float4){sA[2].x, sA[2].y, sA[3].x, sA[3].y};
        *(float4*)&lds[3][w][cb]   = (float4){mA[0].x, mA[0].y, mA[1].x, mA[1].y};
        *(float4*)&lds[3][w][cb+4] = (float4){mA[2].x, mA[2].y, mA[3].x, mA[3].y};
        *(float4*)&lds[4][w][cb]   = (float4){aA[0].x, aA[0].y, aA[1].x, aA[1].y};
        *(float4*)&lds[4][w][cb+4] = (float4){aA[2].x, aA[2].y, aA[3].x, aA[3].y};
        if ((j & 7) == 0) ldsl[w][j >> 3] = lsum;
    }
    __syncthreads();

    const int d = tid;   // output column
    float cs = lds[0][0][d] + lds[0][1][d] + lds[0][2][d] + lds[0][3][d];
    float nm = fmaxf(fmaxf(lds[1][0][d], lds[1][1][d]), fmaxf(lds[1][2][d], lds[1][3][d]));
    float ss = lds[2][0][d] + lds[2][1][d] + lds[2][2][d] + lds[2][3][d];
    float mm = fmaxf(fmaxf(lds[3][0][d], lds[3][1][d]), fmaxf(lds[3][2][d], lds[3][3][d]));
    float ac = lds[4][0][d] + lds[4][1][d] + lds[4][2][d] + lds[4][3][d];
    const int h = d >> 6;
    float denom = ldsl[0][h] + ldsl[1][h] + ldsl[2][h] + ldsl[3][h];
    float att = (denom > 0.f) ? ac / denom : 0.f;

    float* mrow = merged + (size_t)b * 1024;
    mrow[256 + d] = att;
    mrow[512 + d] = mm;
    mrow[768 + d] = ss;
    center  [(size_t)b * DD + d] = cs;
    neighbor[(size_t)b * DD + d] = nm;
}

// ---------------------------------------------------------------------------
// Fused GRU GEMM (unchanged from round 5)
// ---------------------------------------------------------------------------
__global__ __launch_bounds__(256) void gemm_gru(
    const float* __restrict__ center,    // (NB, 256)
    const float* __restrict__ neighbor,  // (NB, 256)
    const float* __restrict__ w_ih,      // (768, 256)
    const float* __restrict__ w_hh,      // (768, 256)
    const float* __restrict__ b_ih,      // (768)
    const float* __restrict__ b_hh,      // (768)
    float* __restrict__ merged)          // (NB, 1024)
{
    __shared__ short Ac[64 * 40];
    __shared__ short An[64 * 40];
    __shared__ short Wt[6][32 * 40];

    const int t   = threadIdx.x;
    const int w   = t >> 6, l = t & 63;
    const int wm  = w >> 1, wn = w & 1;
    const int m0  = blockIdx.x * 64;
    const int j0  = blockIdx.y * 32;
    const int lr  = t >> 2;
    const int lc  = (t & 3) * 8;
    const int wr  = t >> 3;
    const int wc  = (t & 7) * 4;
    const int l15 = l & 15, lq = l >> 4;

    floatx4 acc[6][2] = {};

    for (int k0 = 0; k0 < 256; k0 += 32) {
        const float* cr = &center  [(size_t)(m0 + lr) * 256 + k0 + lc];
        const float* nr = &neighbor[(size_t)(m0 + lr) * 256 + k0 + lc];
        float4 c0 = *(const float4*)cr,  c1 = *(const float4*)(cr + 4);
        float4 e0 = *(const float4*)nr,  e1 = *(const float4*)(nr + 4);
        float4 wv[6];
        #pragma unroll
        for (int gg = 0; gg < 3; ++gg) {
            wv[gg]     = *(const float4*)&w_ih[(size_t)(gg * 256 + j0 + wr) * 256 + k0 + wc];
            wv[gg + 3] = *(const float4*)&w_hh[(size_t)(gg * 256 + j0 + wr) * 256 + k0 + wc];
        }

        __syncthreads();
        short8 a8 = { f2bf(c0.x), f2bf(c0.y), f2bf(c0.z), f2bf(c0.w),
                      f2bf(c1.x), f2bf(c1.y), f2bf(c1.z), f2bf(c1.w) };
        short8 n8 = { f2bf(e0.x), f2bf(e0.y), f2bf(e0.z), f2bf(e0.w),
                      f2bf(e1.x), f2bf(e1.y), f2bf(e1.z), f2bf(e1.w) };
        *(short8*)&Ac[lr * 40 + lc] = a8;
        *(short8*)&An[lr * 40 + lc] = n8;
        #pragma unroll
        for (int gg = 0; gg < 6; ++gg) {
            short4v w4 = { f2bf(wv[gg].x), f2bf(wv[gg].y), f2bf(wv[gg].z), f2bf(wv[gg].w) };
            *(short4v*)&Wt[gg][wr * 40 + wc] = w4;
        }
        __syncthreads();

        short8 afc0 = *(short8*)&Ac[(wm * 32 +      l15) * 40 + lq * 8];
        short8 afc1 = *(short8*)&Ac[(wm * 32 + 16 + l15) * 40 + lq * 8];
        short8 afn0 = *(short8*)&An[(wm * 32 +      l15) * 40 + lq * 8];
        short8 afn1 = *(short8*)&An[(wm * 32 + 16 + l15) * 40 + lq * 8];
        #pragma unroll
        for (int gg = 0; gg < 6; ++gg) {
            short8 bf = *(short8*)&Wt[gg][(wn * 16 + l15) * 40 + lq * 8];
            const short8 x0 = (gg < 3) ? afc0 : afn0;
            const short8 x1 = (gg < 3) ? afc1 : afn1;
            acc[gg][0] = __builtin_amdgcn_mfma_f32_16x16x32_bf16(x0, bf, acc[gg][0], 0, 0, 0);
            acc[gg][1] = __builtin_amdgcn_mfma_f32_16x16x32_bf16(x1, bf, acc[gg][1], 0, 0, 0);
        }
    }

    const int col = j0 + wn * 16 + l15;
    const float bir = b_ih[col], biz = b_ih[256 + col], bin = b_ih[512 + col];
    const float bhr = b_hh[col], bhz = b_hh[256 + col], bhn = b_hh[512 + col];
    #pragma unroll
    for (int i = 0; i < 2; ++i) {
        #pragma unroll
        for (int qq = 0; qq < 4; ++qq) {
            const int row = m0 + wm * 32 + 16 * i + lq * 4 + qq;
            float rr = 1.f / (1.f + __expf(-(acc[0][i][qq] + bir + acc[3][i][qq] + bhr)));
            float zz = 1.f / (1.f + __expf(-(acc[1][i][qq] + biz + acc[4][i][qq] + bhz)));
            float ng = tanhf(acc[2][i][qq] + bin + rr * (acc[5][i][qq] + bhn));
            float nb = neighbor[(size_t)row * 256 + col];
            merged[(size_t)row * 1024 + col] = (1.f - zz) * ng + zz * nb;
        }
    }
}

// ---------------------------------------------------------------------------
// bf16 MFMA GEMM (merge, unchanged)
// ---------------------------------------------------------------------------
__global__ __launch_bounds__(256) void gemm_bf16(
    const float* __restrict__ A, const float* __restrict__ W,
    const float* __restrict__ bias, float* __restrict__ C, int K, int ldc)
{
    __shared__ short As[64 * 40];
    __shared__ short Bs[64 * 40];

    const int t   = threadIdx.x;
    const int w   = t >> 6, l = t & 63;
    const int wm  = w >> 1, wn = w & 1;
    const int m0  = blockIdx.x * 64, n0 = blockIdx.y * 64;
    const int lr  = t >> 2;
    const int lc  = (t & 3) * 8;
    const int l15 = l & 15, lq = l >> 4;

    floatx4 acc[2][2] = {};

    for (int k0 = 0; k0 < K; k0 += 32) {
        const float* ar = &A[(size_t)(m0 + lr) * K + k0 + lc];
        const float* wr = &W[(size_t)(n0 + lr) * K + k0 + lc];
        float4 av0 = *(const float4*)(ar);
        float4 av1 = *(const float4*)(ar + 4);
        float4 wv0 = *(const float4*)(wr);
        float4 wv1 = *(const float4*)(wr + 4);

        __syncthreads();
        short8 a8 = { f2bf(av0.x), f2bf(av0.y), f2bf(av0.z), f2bf(av0.w),
                      f2bf(av1.x), f2bf(av1.y), f2bf(av1.z), f2bf(av1.w) };
        short8 w8 = { f2bf(wv0.x), f2bf(wv0.y), f2bf(wv0.z), f2bf(wv0.w),
                      f2bf(wv1.x), f2bf(wv1.y), f2bf(wv1.z), f2bf(wv1.w) };
        *(short8*)&As[lr * 40 + lc] = a8;
        *(short8*)&Bs[lr * 40 + lc] = w8;
        __syncthreads();

        short8 af0 = *(short8*)&As[(wm * 32 +      l15) * 40 + lq * 8];
        short8 af1 = *(short8*)&As[(wm * 32 + 16 + l15) * 40 + lq * 8];
        short8 bf0 = *(short8*)&Bs[(wn * 32 +      l15) * 40 + lq * 8];
        short8 bf1 = *(short8*)&Bs[(wn * 32 + 16 + l15) * 40 + lq * 8];

        acc[0][0] = __builtin_amdgcn_mfma_f32_16x16x32_bf16(af0, bf0, acc[0][0], 0, 0, 0);
        acc[0][1] = __builtin_amdgcn_mfma_f32_16x16x32_bf16(af0, bf1, acc[0][1], 0, 0, 0);
        acc[1][0] = __builtin_amdgcn_mfma_f32_16x16x32_bf16(af1, bf0, acc[1][0], 0, 0, 0);
        acc[1][1] = __builtin_amdgcn_mfma_f32_16x16x32_bf16(af1, bf1, acc[1][1], 0, 0, 0);
    }

    #pragma unroll
    for (int i = 0; i < 2; ++i) {
        #pragma unroll
        for (int jj = 0; jj < 2; ++jj) {
            const int col = n0 + wn * 32 + 16 * jj + l15;
            const float bv = bias[col];
            #pragma unroll
            for (int qq = 0; qq < 4; ++qq) {
                const int row = m0 + wm * 32 + 16 * i + lq * 4 + qq;
                C[(size_t)row * ldc + col] = acc[i][jj][qq] + bv;
            }
        }
    }
}

// ---------------------------------------------------------------------------
extern "C" void kernel_launch(void* const* d_in, const int* in_sizes, int n_in,
                              void* d_out, int out_size, void* d_ws, size_t ws_size,
                              hipStream_t stream) {
    const float* x       = (const float*)d_in[0];
    const int*   seg     = (const int*)  d_in[1];
    const float* att_w   = (const float*)d_in[2];
    const float* w_ih    = (const float*)d_in[3];
    const float* w_hh    = (const float*)d_in[4];
    const float* b_ih    = (const float*)d_in[5];
    const float* b_hh    = (const float*)d_in[6];
    const float* merge_w = (const float*)d_in[7];
    const float* merge_b = (const float*)d_in[8];
    float* out = (float*)d_out;

    float* ws       = (float*)d_ws;
    float* merged   = ws;                              // 4096*1024
    float* center   = merged   + (size_t)NB * 1024;    // 4096*256
    float* neighbor = center   + (size_t)NB * DD;      // 4096*256

    seg_kernel<<<NB, 256, 0, stream>>>(x, seg, att_w, merged, center, neighbor);

    dim3 gg(NB / 64, DD / 32);
    gemm_gru<<<gg, 256, 0, stream>>>(center, neighbor, w_ih, w_hh, b_ih, b_hh, merged);

    dim3 g2(NB / 64, DD / 64);
    gemm_bf16<<<g2, 256, 0, stream>>>(merged, merge_w, merge_b, out, 1024, DD);
}

// Round 7
// 185.734 us; speedup vs baseline: 1.0437x; 1.0437x over previous
//
#include <hip/hip_runtime.h>
#include <math.h>
#include <stdint.h>

#define NN 500000   // nodes
#define NB 4096     // segments
#define DD 256      // feature dim

typedef short  short8  __attribute__((ext_vector_type(8)));
typedef short  short4v __attribute__((ext_vector_type(4)));
typedef float  floatx4 __attribute__((ext_vector_type(4)));
typedef float  f2      __attribute__((ext_vector_type(2)));

__device__ __forceinline__ f2 sp(float v) { return (f2){v, v}; }

// fp32 -> bf16 round-to-nearest-even
__device__ __forceinline__ short f2bf(float f) {
    uint32_t u = __float_as_uint(f);
    u += 0x7fffu + ((u >> 16) & 1u);
    return (short)(u >> 16);
}

// Packed (2-wide) fast gelu: A&S 7.1.26 erf (|err| <= 1.5e-7), branchless.
__device__ __forceinline__ f2 gelu2(f2 x) {
    f2 z   = __builtin_elementwise_abs(x) * sp(0.70710678118654752440f);
    f2 den = __builtin_elementwise_fma(z, sp(0.3275911f), sp(1.0f));
    f2 t   = { __builtin_amdgcn_rcpf(den.x), __builtin_amdgcn_rcpf(den.y) };
    f2 p   = __builtin_elementwise_fma(sp(1.061405429f), t, sp(-1.453152027f));
    p = __builtin_elementwise_fma(p, t, sp(1.421413741f));
    p = __builtin_elementwise_fma(p, t, sp(-0.284496736f));
    p = __builtin_elementwise_fma(p, t, sp(0.254829592f));
    p = p * t;
    f2 ez  = { __expf(-z.x * z.x), __expf(-z.y * z.y) };
    f2 er  = __builtin_elementwise_copysign(sp(1.0f) - p * ez, x);
    return sp(0.5f) * x * (sp(1.0f) + er);
}

// ---------------------------------------------------------------------------
// Kernel 0: segment boundary precompute. bnd[b] = first row of segment b;
// bnd[NB] = NN. Covers empty segments by the range-fill construction.
// ---------------------------------------------------------------------------
__global__ __launch_bounds__(256) void seg_bounds(
    const int* __restrict__ seg, int* __restrict__ bnd)
{
    int i = blockIdx.x * 256 + threadIdx.x;
    if (i >= NN) return;
    int s = seg[i];
    if (i == 0) {
        for (int b = 0; b <= s; ++b) bnd[b] = 0;
    } else {
        int p = seg[i - 1];
        for (int b = p + 1; b <= s; ++b) bnd[b] = i;
    }
    if (i == NN - 1) {
        for (int b = s + 1; b <= NB; ++b) bnd[b] = NN;
    }
}

// ---------------------------------------------------------------------------
// Kernel 1 (round-5 structure + bnd + 3-deep prefetch): one block (4 waves)
// per segment; wave w owns a contiguous chunk of rows, lane l owns cols
// 4l..4l+3 (float4 = full row per wave). 2 rows processed/iter, 6 rows
// resident. Head h = l>>4 (16 lanes/head). Plain-exp segment softmax.
// ---------------------------------------------------------------------------
__global__ __launch_bounds__(256) void seg_kernel(
    const float* __restrict__ x,
    const int*   __restrict__ bnd,
    const float* __restrict__ att_w,
    float* __restrict__ merged,    // (NB, 1024)
    float* __restrict__ center,    // (NB, 256)
    float* __restrict__ neighbor)  // (NB, 256)
{
    const int b   = blockIdx.x;
    const int tid = threadIdx.x;
    const int w   = tid >> 6;     // wave 0..3
    const int l   = tid & 63;     // lane

    const int start = bnd[b];
    const int end   = bnd[b + 1];

    // contiguous chunk for this wave
    const int cnt = end - start;
    const int q = cnt >> 2, r = cnt & 3;
    const int my_start = start + w * q + (w < r ? w : r);
    const int my_cnt   = q + (w < r ? 1 : 0);

    const float4 awv = *reinterpret_cast<const float4*>(&att_w[4 * l]);
    const f2 aw01 = {awv.x, awv.y}, aw23 = {awv.z, awv.w};

    f2 c01 = sp(0.f), c23 = sp(0.f);                 // segsum(gelu)
    f2 n01 = sp(-INFINITY), n23 = sp(-INFINITY);     // segmax(gelu)
    f2 s01 = sp(0.f), s23 = sp(0.f);                 // segsum(x)
    f2 m01 = sp(-INFINITY), m23 = sp(-INFINITY);     // segmax(x)
    f2 a01 = sp(0.f), a23 = sp(0.f);                 // sum e*x
    float lsum = 0.f;                                 // sum e (per head)

    auto process = [&](const float4& v) {
        f2 vl = {v.x, v.y}, vh = {v.z, v.w};
        f2 gl = gelu2(vl), gh = gelu2(vh);
        c01 += gl; c23 += gh;
        n01 = __builtin_elementwise_max(n01, gl);
        n23 = __builtin_elementwise_max(n23, gh);
        s01 += vl; s23 += vh;
        m01 = __builtin_elementwise_max(m01, vl);
        m23 = __builtin_elementwise_max(m23, vh);
        f2 tp = __builtin_elementwise_fma(vh, aw23, vl * aw01);
        float t = tp.x + tp.y;
        t += __shfl_xor(t, 1, 64);
        t += __shfl_xor(t, 2, 64);
        t += __shfl_xor(t, 4, 64);
        t += __shfl_xor(t, 8, 64);
        float alpha = fmaxf(t, 0.2f * t);   // leaky_relu(0.2), branchless
        float e = __expf(alpha);            // no max-shift: |alpha| small
        lsum += e;
        f2 ev = sp(e);
        a01 = __builtin_elementwise_fma(ev, vl, a01);
        a23 = __builtin_elementwise_fma(ev, vh, a23);
    };

    const float* __restrict__ xl = x + 4 * l;
    auto LD = [&](int row) -> float4 {
        int rc = row < (NN - 1) ? row : (NN - 1);   // clamp: over-reads discarded
        return *reinterpret_cast<const float4*>(&xl[(size_t)rc * DD]);
    };

    // 6 rows resident, 2 processed per iteration, prefetch 4..6 ahead
    float4 q0 = LD(my_start),     q1 = LD(my_start + 1),
           q2 = LD(my_start + 2), q3 = LD(my_start + 3),
           q4 = LD(my_start + 4), q5 = LD(my_start + 5);
    int ip = my_start + 6;
    int rem = my_cnt;
    while (rem >= 2) {
        float4 f0 = LD(ip), f1 = LD(ip + 1);
        process(q0); process(q1);
        q0 = q2; q1 = q3; q2 = q4; q3 = q5; q4 = f0; q5 = f1;
        ip += 2; rem -= 2;
    }
    if (rem) process(q0);

    // ---- cross-wave combine ----
    __shared__ float lds[5][4][256];   // c, n, s, m, a  (20 KB)
    __shared__ float ldsl[4][4];       // per-wave per-head denom partials
    const int c = 4 * l;
    lds[0][w][c+0] = c01.x; lds[0][w][c+1] = c01.y; lds[0][w][c+2] = c23.x; lds[0][w][c+3] = c23.y;
    lds[1][w][c+0] = n01.x; lds[1][w][c+1] = n01.y; lds[1][w][c+2] = n23.x; lds[1][w][c+3] = n23.y;
    lds[2][w][c+0] = s01.x; lds[2][w][c+1] = s01.y; lds[2][w][c+2] = s23.x; lds[2][w][c+3] = s23.y;
    lds[3][w][c+0] = m01.x; lds[3][w][c+1] = m01.y; lds[3][w][c+2] = m23.x; lds[3][w][c+3] = m23.y;
    lds[4][w][c+0] = a01.x; lds[4][w][c+1] = a01.y; lds[4][w][c+2] = a23.x; lds[4][w][c+3] = a23.y;
    if ((l & 15) == 0) ldsl[w][l >> 4] = lsum;
    __syncthreads();

    const int d = tid;   // output column
    float cs = lds[0][0][d] + lds[0][1][d] + lds[0][2][d] + lds[0][3][d];
    float nm = fmaxf(fmaxf(lds[1][0][d], lds[1][1][d]), fmaxf(lds[1][2][d], lds[1][3][d]));
    float ss = lds[2][0][d] + lds[2][1][d] + lds[2][2][d] + lds[2][3][d];
    float mm = fmaxf(fmaxf(lds[3][0][d], lds[3][1][d]), fmaxf(lds[3][2][d], lds[3][3][d]));
    float ac = lds[4][0][d] + lds[4][1][d] + lds[4][2][d] + lds[4][3][d];
    const int h = d >> 6;
    float denom = ldsl[0][h] + ldsl[1][h] + ldsl[2][h] + ldsl[3][h];
    float att = (denom > 0.f) ? ac / denom : 0.f;

    float* mrow = merged + (size_t)b * 1024;
    mrow[256 + d] = att;
    mrow[512 + d] = mm;
    mrow[768 + d] = ss;
    center  [(size_t)b * DD + d] = cs;
    neighbor[(size_t)b * DD + d] = nm;
}

// ---------------------------------------------------------------------------
// Fused GRU GEMM (unchanged)
// ---------------------------------------------------------------------------
__global__ __launch_bounds__(256) void gemm_gru(
    const float* __restrict__ center,    // (NB, 256)
    const float* __restrict__ neighbor,  // (NB, 256)
    const float* __restrict__ w_ih,      // (768, 256)
    const float* __restrict__ w_hh,      // (768, 256)
    const float* __restrict__ b_ih,      // (768)
    const float* __restrict__ b_hh,      // (768)
    float* __restrict__ merged)          // (NB, 1024)
{
    __shared__ short Ac[64 * 40];
    __shared__ short An[64 * 40];
    __shared__ short Wt[6][32 * 40];

    const int t   = threadIdx.x;
    const int w   = t >> 6, l = t & 63;
    const int wm  = w >> 1, wn = w & 1;
    const int m0  = blockIdx.x * 64;
    const int j0  = blockIdx.y * 32;
    const int lr  = t >> 2;
    const int lc  = (t & 3) * 8;
    const int wr  = t >> 3;
    const int wc  = (t & 7) * 4;
    const int l15 = l & 15, lq = l >> 4;

    floatx4 acc[6][2] = {};

    for (int k0 = 0; k0 < 256; k0 += 32) {
        const float* cr = &center  [(size_t)(m0 + lr) * 256 + k0 + lc];
        const float* nr = &neighbor[(size_t)(m0 + lr) * 256 + k0 + lc];
        float4 c0 = *(const float4*)cr,  c1 = *(const float4*)(cr + 4);
        float4 e0 = *(const float4*)nr,  e1 = *(const float4*)(nr + 4);
        float4 wv[6];
        #pragma unroll
        for (int gg = 0; gg < 3; ++gg) {
            wv[gg]     = *(const float4*)&w_ih[(size_t)(gg * 256 + j0 + wr) * 256 + k0 + wc];
            wv[gg + 3] = *(const float4*)&w_hh[(size_t)(gg * 256 + j0 + wr) * 256 + k0 + wc];
        }

        __syncthreads();
        short8 a8 = { f2bf(c0.x), f2bf(c0.y), f2bf(c0.z), f2bf(c0.w),
                      f2bf(c1.x), f2bf(c1.y), f2bf(c1.z), f2bf(c1.w) };
        short8 n8 = { f2bf(e0.x), f2bf(e0.y), f2bf(e0.z), f2bf(e0.w),
                      f2bf(e1.x), f2bf(e1.y), f2bf(e1.z), f2bf(e1.w) };
        *(short8*)&Ac[lr * 40 + lc] = a8;
        *(short8*)&An[lr * 40 + lc] = n8;
        #pragma unroll
        for (int gg = 0; gg < 6; ++gg) {
            short4v w4 = { f2bf(wv[gg].x), f2bf(wv[gg].y), f2bf(wv[gg].z), f2bf(wv[gg].w) };
            *(short4v*)&Wt[gg][wr * 40 + wc] = w4;
        }
        __syncthreads();

        short8 afc0 = *(short8*)&Ac[(wm * 32 +      l15) * 40 + lq * 8];
        short8 afc1 = *(short8*)&Ac[(wm * 32 + 16 + l15) * 40 + lq * 8];
        short8 afn0 = *(short8*)&An[(wm * 32 +      l15) * 40 + lq * 8];
        short8 afn1 = *(short8*)&An[(wm * 32 + 16 + l15) * 40 + lq * 8];
        #pragma unroll
        for (int gg = 0; gg < 6; ++gg) {
            short8 bf = *(short8*)&Wt[gg][(wn * 16 + l15) * 40 + lq * 8];
            const short8 x0 = (gg < 3) ? afc0 : afn0;
            const short8 x1 = (gg < 3) ? afc1 : afn1;
            acc[gg][0] = __builtin_amdgcn_mfma_f32_16x16x32_bf16(x0, bf, acc[gg][0], 0, 0, 0);
            acc[gg][1] = __builtin_amdgcn_mfma_f32_16x16x32_bf16(x1, bf, acc[gg][1], 0, 0, 0);
        }
    }

    const int col = j0 + wn * 16 + l15;
    const float bir = b_ih[col], biz = b_ih[256 + col], bin = b_ih[512 + col];
    const float bhr = b_hh[col], bhz = b_hh[256 + col], bhn = b_hh[512 + col];
    #pragma unroll
    for (int i = 0; i < 2; ++i) {
        #pragma unroll
        for (int qq = 0; qq < 4; ++qq) {
            const int row = m0 + wm * 32 + 16 * i + lq * 4 + qq;
            float rr = 1.f / (1.f + __expf(-(acc[0][i][qq] + bir + acc[3][i][qq] + bhr)));
            float zz = 1.f / (1.f + __expf(-(acc[1][i][qq] + biz + acc[4][i][qq] + bhz)));
            float ng = tanhf(acc[2][i][qq] + bin + rr * (acc[5][i][qq] + bhn));
            float nb = neighbor[(size_t)row * 256 + col];
            merged[(size_t)row * 1024 + col] = (1.f - zz) * ng + zz * nb;
        }
    }
}

// ---------------------------------------------------------------------------
// bf16 MFMA GEMM (merge, unchanged)
// ---------------------------------------------------------------------------
__global__ __launch_bounds__(256) void gemm_bf16(
    const float* __restrict__ A, const float* __restrict__ W,
    const float* __restrict__ bias, float* __restrict__ C, int K, int ldc)
{
    __shared__ short As[64 * 40];
    __shared__ short Bs[64 * 40];

    const int t   = threadIdx.x;
    const int w   = t >> 6, l = t & 63;
    const int wm  = w >> 1, wn = w & 1;
    const int m0  = blockIdx.x * 64, n0 = blockIdx.y * 64;
    const int lr  = t >> 2;
    const int lc  = (t & 3) * 8;
    const int l15 = l & 15, lq = l >> 4;

    floatx4 acc[2][2] = {};

    for (int k0 = 0; k0 < K; k0 += 32) {
        const float* ar = &A[(size_t)(m0 + lr) * K + k0 + lc];
        const float* wr = &W[(size_t)(n0 + lr) * K + k0 + lc];
        float4 av0 = *(const float4*)(ar);
        float4 av1 = *(const float4*)(ar + 4);
        float4 wv0 = *(const float4*)(wr);
        float4 wv1 = *(const float4*)(wr + 4);

        __syncthreads();
        short8 a8 = { f2bf(av0.x), f2bf(av0.y), f2bf(av0.z), f2bf(av0.w),
                      f2bf(av1.x), f2bf(av1.y), f2bf(av1.z), f2bf(av1.w) };
        short8 w8 = { f2bf(wv0.x), f2bf(wv0.y), f2bf(wv0.z), f2bf(wv0.w),
                      f2bf(wv1.x), f2bf(wv1.y), f2bf(wv1.z), f2bf(wv1.w) };
        *(short8*)&As[lr * 40 + lc] = a8;
        *(short8*)&Bs[lr * 40 + lc] = w8;
        __syncthreads();

        short8 af0 = *(short8*)&As[(wm * 32 +      l15) * 40 + lq * 8];
        short8 af1 = *(short8*)&As[(wm * 32 + 16 + l15) * 40 + lq * 8];
        short8 bf0 = *(short8*)&Bs[(wn * 32 +      l15) * 40 + lq * 8];
        short8 bf1 = *(short8*)&Bs[(wn * 32 + 16 + l15) * 40 + lq * 8];

        acc[0][0] = __builtin_amdgcn_mfma_f32_16x16x32_bf16(af0, bf0, acc[0][0], 0, 0, 0);
        acc[0][1] = __builtin_amdgcn_mfma_f32_16x16x32_bf16(af0, bf1, acc[0][1], 0, 0, 0);
        acc[1][0] = __builtin_amdgcn_mfma_f32_16x16x32_bf16(af1, bf0, acc[1][0], 0, 0, 0);
        acc[1][1] = __builtin_amdgcn_mfma_f32_16x16x32_bf16(af1, bf1, acc[1][1], 0, 0, 0);
    }

    #pragma unroll
    for (int i = 0; i < 2; ++i) {
        #pragma unroll
        for (int jj = 0; jj < 2; ++jj) {
            const int col = n0 + wn * 32 + 16 * jj + l15;
            const float bv = bias[col];
            #pragma unroll
            for (int qq = 0; qq < 4; ++qq) {
                const int row = m0 + wm * 32 + 16 * i + lq * 4 + qq;
                C[(size_t)row * ldc + col] = acc[i][jj][qq] + bv;
            }
        }
    }
}

// ---------------------------------------------------------------------------
extern "C" void kernel_launch(void* const* d_in, const int* in_sizes, int n_in,
                              void* d_out, int out_size, void* d_ws, size_t ws_size,
                              hipStream_t stream) {
    const float* x       = (const float*)d_in[0];
    const int*   seg     = (const int*)  d_in[1];
    const float* att_w   = (const float*)d_in[2];
    const float* w_ih    = (const float*)d_in[3];
    const float* w_hh    = (const float*)d_in[4];
    const float* b_ih    = (const float*)d_in[5];
    const float* b_hh    = (const float*)d_in[6];
    const float* merge_w = (const float*)d_in[7];
    const float* merge_b = (const float*)d_in[8];
    float* out = (float*)d_out;

    float* ws       = (float*)d_ws;
    float* merged   = ws;                              // 4096*1024
    float* center   = merged   + (size_t)NB * 1024;    // 4096*256
    float* neighbor = center   + (size_t)NB * DD;      // 4096*256
    int*   bnd      = (int*)(neighbor + (size_t)NB * DD);  // 4097 ints

    seg_bounds<<<(NN + 255) / 256, 256, 0, stream>>>(seg, bnd);

    seg_kernel<<<NB, 256, 0, stream>>>(x, bnd, att_w, merged, center, neighbor);

    dim3 gg(NB / 64, DD / 32);
    gemm_gru<<<gg, 256, 0, stream>>>(center, neighbor, w_ih, w_hh, b_ih, b_hh, merged);

    dim3 g2(NB / 64, DD / 64);
    gemm_bf16<<<g2, 256, 0, stream>>>(merged, merge_w, merge_b, out, 1024, DD);
}